// Round 8
// baseline (153.254 us; speedup 1.0000x reference)
//
#include <hip/hip_runtime.h>
#include <hip/hip_bf16.h>
#include <math.h>

// Channel attention: x (2,16,16,16,64) fp32 -> B=2, N=4096, C=64.
// out = gamma * softmax(QQ^T) Q + x.
// v22: DIAGNOSTIC ROUND. Seven structural rewrites (v14-v21) all null at
// ~82us; both surviving cost models contradicted by v16~=v19; the staged
// attn has NEVER appeared in the top-5 counter table (it sits below the
// ~42us harness fills). This round runs attn's K-loop REPS=3 times
// (acc/l re-zeroed per rep -> output identical) so attn ~70us tops the
// table and we finally get its PMC signature. Pre-registered reads:
// (1) rep3 ~70us => per-pass work real; ~30-40us => dispatch overhead.
// (2) all-util-low => latency/queue on staging -> deepen prefetch.
// (3) VALUBusy>=45% => exp2/VALU chain -> attack VALU.
// (4) LDS_BANK_CONFLICT huge => swizzle wrong.
// (5) FETCH >> 40MB => cross-XCD dirty handoff to HBM -> read x directly.
// Base kernel = v21 verbatim (32x32x16, 128-row blocks, 128-key super-
// tiles, register P^T, depth-2 counted vmcnt, XCD-colocated prep).
// Fixed harness floor: ~42us d_ws re-poison fill inside the timed window.

#define NN 4096
#define CC 64
#define LOG2E 1.4426950408889634f

typedef __attribute__((ext_vector_type(4))) float f32x4;
typedef __attribute__((ext_vector_type(16))) float f32x16;
typedef __attribute__((ext_vector_type(8))) short bf16x8;
typedef __attribute__((ext_vector_type(4))) short bf16x4;
typedef unsigned short u16;
typedef __attribute__((ext_vector_type(4))) u16 u16x4;
typedef __attribute__((ext_vector_type(8))) u16 u16x8;
typedef __attribute__((ext_vector_type(2))) unsigned u32x2;

__device__ inline u16 f2bf(float f) {  // RNE
  union { float f; unsigned u; } v; v.f = f;
  unsigned r = (v.u + 0x7fffu + ((v.u >> 16) & 1u)) >> 16;
  return (u16)r;
}
__device__ inline float bf2f(short h) {
  union { unsigned u; float f; } v;
  v.u = ((unsigned)(unsigned short)h) << 16;
  return v.f;
}
__device__ inline unsigned fbits(float f) {
  union { float f; unsigned u; } v; v.f = f;
  return v.u;
}
__device__ inline unsigned cvtpk(float lo, float hi) {  // {bf16(lo)|bf16(hi)<<16}
  unsigned d;
  asm("v_cvt_pk_bf16_f32 %0, %1, %2" : "=v"(d) : "v"(lo), "v"(hi));
  return d;
}
__device__ inline bf16x8 cvt8(f32x4 a, f32x4 b) {
  bf16x8 r;
  r[0] = (short)f2bf(a[0]); r[1] = (short)f2bf(a[1]);
  r[2] = (short)f2bf(a[2]); r[3] = (short)f2bf(a[3]);
  r[4] = (short)f2bf(b[0]); r[5] = (short)f2bf(b[1]);
  r[6] = (short)f2bf(b[2]); r[7] = (short)f2bf(b[3]);
  return r;
}

// ---------------------------------------------------------------------------
// Prep: x -> bf16 Qb[b][n][c] and Vt2[b][n/64][c][n%64]. 512 blocks x 256.
// v21 XCD-colocating block->tile permutation (kept; harmless).
// ---------------------------------------------------------------------------
__global__ __launch_bounds__(256) void prep_kernel(const float* __restrict__ x,
                                                   u16* __restrict__ Qb,
                                                   u16* __restrict__ Vt) {
  __shared__ u16 t[64][20];
  int p = blockIdx.x;                // [0, 512)
  int x8 = p & 7;                    // key-slice == target XCD
  int q = p >> 3;                    // [0, 64)
  int b = q >> 5;                    // batch
  int tl = x8 * 32 + (q & 31);       // tile within batch [0, 256)
  int n0 = tl << 4;                  // 16-row tile
  const f32x4* x4 = (const f32x4*)(x + ((size_t)b * NN + n0) * CC);
  u16* qb = Qb + ((size_t)b * NN + n0) * CC;
  {
    int idx4 = threadIdx.x;          // 256 f32x4 = 16 rows x 16 groups
    int i = idx4 >> 4, cg = idx4 & 15;
    f32x4 v = x4[idx4];
    u16x4 h;
    h[0] = f2bf(v[0]); h[1] = f2bf(v[1]); h[2] = f2bf(v[2]); h[3] = f2bf(v[3]);
    *(u16x4*)(qb + (size_t)i * CC + cg * 4) = h;
    t[cg * 4 + 0][i] = h[0]; t[cg * 4 + 1][i] = h[1];
    t[cg * 4 + 2][i] = h[2]; t[cg * 4 + 3][i] = h[3];
  }
  __syncthreads();
  int kb = n0 >> 6, kw0 = n0 & 63;   // 64-key block / offset within it
  {
    int idx4 = threadIdx.x;          // 256 u16x4 = 64 c x 4 i-groups
    int c = idx4 >> 2, i4 = (idx4 & 3) * 4;
    u16x4 h = *(const u16x4*)(&t[c][i4]);
    *(u16x4*)(Vt + (((size_t)b * (NN / 64) + kb) * 64 + c) * 64 + kw0 + i4) = h;
  }
}

// ---------------------------------------------------------------------------
// Split flash (v21 body + REPS diagnostic loop).
// ---------------------------------------------------------------------------
template <int S, int REPS>
__global__ __launch_bounds__(512, 4) void attn_split(
    const u16* __restrict__ Qb, const u16* __restrict__ Vt,
    u16* __restrict__ Opart, float* __restrict__ lpart) {
  constexpr int KPS = NN / S;        // 512
  constexpr int ITERS = KPS / 128;   // 4 super-tiles
  const int lane = threadIdx.x & 63;
  const int w = threadIdx.x >> 6;    // 0..7
  const int wk = w & 1, wr4 = w >> 1;
  const int hf = lane >> 5, l31 = lane & 31, c8 = lane & 7;
  const int blk = blockIdx.x;        // [0, 2*32*S)
  const int b = blk / (32 * S);
  const int rg = (blk / S) & 31;
  const int s = blk % S;

  __shared__ __align__(16) char smem[65536];
  u16* KT = (u16*)smem;              // [2][2][64 keys][64 ch]
  u16* VT = (u16*)(smem + 32768);    // [2][2][64 ch][64 keys]

  const u16* Qbase = Qb + (size_t)b * NN * CC;
  const u16* Vbase = Vt + (size_t)b * NN * CC;  // [NN/64][64][64]
  const int row0 = rg * 128 + wr4 * 32;

  // --- Q B-frags (pre-scaled by log2e), m = diag of scaled S (per-lane) ---
  bf16x8 qs[4];
  float m_sc;
  {
    const u16* qp = Qbase + (size_t)(row0 + l31) * CC + hf * 8;
    float msum = 0.f;
#pragma unroll
    for (int sl = 0; sl < 4; ++sl) {
      bf16x8 r0 = *(const bf16x8*)(qp + sl * 16);
      bf16x8 t;
#pragma unroll
      for (int j = 0; j < 8; ++j) {
        float a = bf2f(r0[j]);
        u16 hs = f2bf(a * LOG2E);
        t[j] = (short)hs;
        msum += bf2f((short)hs) * a;
      }
      qs[sl] = t;
    }
    msum += __shfl_xor(msum, 32);    // partner holds the other 32 ch
    m_sc = msum;
  }

  f32x16 zero16;
#pragma unroll
  for (int r = 0; r < 16; ++r) zero16[r] = 0.f;
  f32x16 acc[2];
  float l_loc;

  // --- staging: wave w covers rows [w*8, w*8+8) of each 64x64 sub-tile ---
  const int g8 = lane >> 3;          // 0..7 local row in the wave's 8-row group
  const int swz = c8 ^ g8;           // pre-swizzled 16B chunk (chunk^row&7)
  const u16* kptr = Qbase + (size_t)(s * KPS + w * 8 + g8) * CC + swz * 8;
  const u16* vptr = Vbase + (size_t)(s * (KPS >> 6)) * 4096 + (size_t)(w * 8 + g8) * 64 + swz * 8;

  // super-tile it (128 keys): halves h=0,1 at source offset it*8192 + h*4096.
#define STAGE(p, it)                                                          \
  {                                                                           \
    _Pragma("unroll")                                                         \
    for (int h = 0; h < 2; ++h) {                                             \
      __builtin_amdgcn_global_load_lds(                                       \
          (const __attribute__((address_space(1))) unsigned*)(kptr + (size_t)(it) * 8192 + h * 4096), \
          (__attribute__((address_space(3))) unsigned*)&KT[((p) * 2 + h) * 4096 + (w * 8) * 64], 16, 0, 0); \
      __builtin_amdgcn_global_load_lds(                                       \
          (const __attribute__((address_space(1))) unsigned*)(vptr + (size_t)(it) * 8192 + h * 4096), \
          (__attribute__((address_space(3))) unsigned*)&VT[((p) * 2 + h) * 4096 + (w * 8) * 64], 16, 0, 0); \
    }                                                                         \
  }

#pragma unroll 1
  for (int rep = 0; rep < REPS; ++rep) {
    acc[0] = zero16; acc[1] = zero16; l_loc = 0.f;
    STAGE(0, 0)                      // 4 gll outstanding
    STAGE(1, 1)                      // 8 outstanding

#pragma unroll
    for (int i = 0; i < ITERS; ++i) {
      // super-tile i's 4 gll done; tile i+1's 4 stay in flight.
      if (i + 1 < ITERS)
        asm volatile("s_waitcnt vmcnt(4)" ::: "memory");
      else
        asm volatile("s_waitcnt vmcnt(0)" ::: "memory");
      __builtin_amdgcn_sched_barrier(0);
      __builtin_amdgcn_s_barrier();  // all waves: super-tile i in LDS
      __builtin_amdgcn_sched_barrier(0);
      const int p = i & 1;

#pragma unroll
      for (int h = 0; h < 2; ++h) {  // two 64-key halves
        const u16* KTp = KT + (p * 2 + h) * 4096;
        const u16* VTp = VT + (p * 2 + h) * 4096;

        // --- QK^T (S^T form): sx[key 16-pat][qrow=l31], keys = wk-half ---
        f32x16 sx = zero16;
        __builtin_amdgcn_s_setprio(1);
#pragma unroll
        for (int sl = 0; sl < 4; ++sl) {
          bf16x8 kf = *(const bf16x8*)&KTp[(wk * 32 + l31) * 64 + ((sl * 2 + hf) ^ c8) * 8];
          sx = __builtin_amdgcn_mfma_f32_32x32x16_bf16(kf, qs[sl], sx, 0, 0, 0);
        }
        __builtin_amdgcn_s_setprio(0);

        // --- exp2 + l + in-register P^T frags (keys (r&3)+8*(r>>2)+4*hf) ---
        float p16[16];
#pragma unroll
        for (int r = 0; r < 16; ++r) p16[r] = exp2f(sx[r] - m_sc);
#pragma unroll
        for (int r = 0; r < 16; ++r) l_loc += p16[r];
        unsigned own[4][2], sh[4][2];
#pragma unroll
        for (int q = 0; q < 4; ++q) {  // quad q = keys 8q+4hf+0..3
          own[q][0] = cvtpk(p16[4 * q + 0], p16[4 * q + 1]);
          own[q][1] = cvtpk(p16[4 * q + 2], p16[4 * q + 3]);
        }
#pragma unroll
        for (int q = 0; q < 4; ++q) {
          sh[q][0] = (unsigned)__shfl_xor((int)own[q][0], 32);
          sh[q][1] = (unsigned)__shfl_xor((int)own[q][1], 32);
        }
        bf16x8 pf[2];                // B-frag ks: keys 16ks+8hf+0..7
#pragma unroll
        for (int ks = 0; ks < 2; ++ks) {
          unsigned d0 = hf ? sh[2 * ks + 1][0] : own[2 * ks][0];
          unsigned d1 = hf ? sh[2 * ks + 1][1] : own[2 * ks][1];
          unsigned d2 = hf ? own[2 * ks + 1][0] : sh[2 * ks][0];
          unsigned d3 = hf ? own[2 * ks + 1][1] : sh[2 * ks][1];
          bf16x8 f;
          ((unsigned*)&f)[0] = d0; ((unsigned*)&f)[1] = d1;
          ((unsigned*)&f)[2] = d2; ((unsigned*)&f)[3] = d3;
          pf[ks] = f;
        }

        // --- PV (O^T form): acc[cg] += V^T[ch][key] * P^T[key][qrow] ---
        __builtin_amdgcn_s_setprio(1);
#pragma unroll
        for (int cg = 0; cg < 2; ++cg) {
#pragma unroll
          for (int ks = 0; ks < 2; ++ks) {
            bf16x8 vf = *(const bf16x8*)&VTp[(cg * 32 + l31) * 64 + ((4 * wk + 2 * ks + hf) ^ c8) * 8];
            acc[cg] = __builtin_amdgcn_mfma_f32_32x32x16_bf16(vf, pf[ks], acc[cg], 0, 0, 0);
          }
        }
        __builtin_amdgcn_s_setprio(0);
      }
      // all waves done reading buffer p before super-tile i+2 overwrites it
      __builtin_amdgcn_sched_barrier(0);
      __builtin_amdgcn_s_barrier();
      __builtin_amdgcn_sched_barrier(0);
      if (i + 2 < ITERS) STAGE(p, i + 2)
    }
  }
#undef STAGE

  // --- combine wk partials + transpose via LDS (reuses staging space) ---
  l_loc += __shfl_xor(l_loc, 32);    // partner half holds other 16 keys
  float* LDSO = (float*)smem;        // [64 ch][132] padded (33792 B)
  float* LDSL = (float*)(smem + 64 * 132 * 4);  // [2][128]
  const int qcol = wr4 * 32 + l31;   // 0..127
  if (wk == 1) {
#pragma unroll
    for (int cg = 0; cg < 2; ++cg)
#pragma unroll
      for (int r = 0; r < 16; ++r) {
        int ch = cg * 32 + (r & 3) + 8 * (r >> 2) + 4 * hf;
        LDSO[ch * 132 + qcol] = acc[cg][r];
      }
  }
  if (lane < 32) LDSL[wk * 128 + qcol] = l_loc;
  __syncthreads();
  if (wk == 0) {
#pragma unroll
    for (int cg = 0; cg < 2; ++cg)
#pragma unroll
      for (int r = 0; r < 16; ++r) {
        int ch = cg * 32 + (r & 3) + 8 * (r >> 2) + 4 * hf;
        LDSO[ch * 132 + qcol] += acc[cg][r];
      }
  }
  __syncthreads();

  size_t pbase = (((size_t)(b * 32 + rg)) * S + s) * (128 * 64);
  size_t lbase = (((size_t)(b * 32 + rg)) * S + s) * 128;
  {
    int row = threadIdx.x >> 2;      // 0..127 (q-row)
    int cq = threadIdx.x & 3;        // 16-ch chunk
    u16x8 o0, o1;
#pragma unroll
    for (int j = 0; j < 8; ++j) {
      o0[j] = f2bf(LDSO[(cq * 16 + j) * 132 + row]);
      o1[j] = f2bf(LDSO[(cq * 16 + 8 + j) * 132 + row]);
    }
    *(u16x8*)(Opart + pbase + (size_t)row * 64 + cq * 16) = o0;
    *(u16x8*)(Opart + pbase + (size_t)row * 64 + cq * 16 + 8) = o1;
  }
  if (threadIdx.x < 128)
    lpart[lbase + threadIdx.x] = LDSL[threadIdx.x] + LDSL[128 + threadIdx.x];
}

// ---------------------------------------------------------------------------
// Epilogue: out = gamma * (sum_s O)/(sum_s l) + x. 512 blocks x 256 threads.
// Opart layout [b][rg=32][S][128][64].
// ---------------------------------------------------------------------------
template <int S>
__global__ __launch_bounds__(256) void epi_kernel(
    const float* __restrict__ x, const float* __restrict__ gamma,
    const u16* __restrict__ Opart, const float* __restrict__ lpart,
    float* __restrict__ out) {
  int t = blockIdx.x * 256 + threadIdx.x;  // [0, B*NN*16)
  int cg = t & 15;
  int n = (t >> 4) & (NN - 1);
  int b = t >> 16;
  int rb = n >> 7, lr = n & 127;
  size_t obase = ((size_t)(b * 32 + rb) * S) * 8192 + (size_t)lr * 64 + cg * 4;
  size_t lbase = ((size_t)(b * 32 + rb) * S) * 128 + lr;
  f32x4 sO = {0.f, 0.f, 0.f, 0.f};
  float sL = 0.f;
#pragma unroll
  for (int s = 0; s < S; ++s) {
    u16x4 o4 = *(const u16x4*)(Opart + obase + (size_t)s * 8192);
    sL += lpart[lbase + (size_t)s * 128];
    sO[0] += bf2f((short)o4[0]); sO[1] += bf2f((short)o4[1]);
    sO[2] += bf2f((short)o4[2]); sO[3] += bf2f((short)o4[3]);
  }
  size_t xi = (((size_t)b * NN + n) * CC + cg * 4);
  f32x4 xv = *(const f32x4*)(x + xi);
  float g = gamma[0], inv = 1.f / sL;
  f32x4 ov;
#pragma unroll
  for (int j = 0; j < 4; ++j) ov[j] = g * (sO[j] * inv) + xv[j];
  *(f32x4*)(((float*)out) + xi) = ov;
}

// ---------------------------------------------------------------------------
// Tier B (2MB <= ws): single-kernel path. Tier C: workspace-free.
// ---------------------------------------------------------------------------
template <int WPB>
__global__ __launch_bounds__(WPB * 64, 4) void attn_fast(
    const float* __restrict__ x, const float* __restrict__ gamma,
    const u16* __restrict__ Qb, const u16* __restrict__ Vt,
    float* __restrict__ out) {
  const int w = threadIdx.x >> 6;
  const int lane = threadIdx.x & 63;
  const int quad = lane >> 4, col = lane & 15;
  const int b = blockIdx.x >> 8;
  const int tile = (blockIdx.x & 255) << 4;

  extern __shared__ char smem[];
  float* Osh = (float*)smem;
  float* lsh = Osh + WPB * 1024;
  u16* pl = (u16*)(lsh + WPB * 16) + w * 2176;

  const size_t xoff = (size_t)b * NN * CC;
  const u16* Qbase = Qb + xoff;
  const u16* Vbase = Vt + xoff;

  bf16x8 qf0 = *(const bf16x8*)(Qbase + (size_t)(tile + col) * CC + quad * 8);
  bf16x8 qf1 = *(const bf16x8*)(Qbase + (size_t)(tile + col) * CC + 32 + quad * 8);

  float msum = 0.f;
#pragma unroll
  for (int j = 0; j < 8; ++j) {
    float a = bf2f(qf0[j]), c = bf2f(qf1[j]);
    msum += a * a + c * c;
  }
  msum += __shfl_xor(msum, 16);
  msum += __shfl_xor(msum, 32);
  float m_i[4];
#pragma unroll
  for (int r = 0; r < 4; ++r) m_i[r] = __shfl(msum, quad * 4 + r);

  f32x4 zero = {0.f, 0.f, 0.f, 0.f};
  f32x4 acc[4] = {zero, zero, zero, zero};
  float l_i[4] = {0.f, 0.f, 0.f, 0.f};

  const int k0 = w * (NN / WPB);
#pragma unroll 2
  for (int kt = k0; kt < k0 + NN / WPB; kt += 64) {
    u16* plc = pl + ((kt >> 6) & 1) * 1088;
    f32x4 sx[4];
#pragma unroll
    for (int t = 0; t < 4; ++t) {
      const u16* kp = Qbase + (size_t)(kt + t * 16 + col) * CC + quad * 8;
      bf16x8 ka = *(const bf16x8*)kp;
      bf16x8 kb = *(const bf16x8*)(kp + 32);
      sx[t] = __builtin_amdgcn_mfma_f32_16x16x32_bf16(qf0, ka, zero, 0, 0, 0);
      sx[t] = __builtin_amdgcn_mfma_f32_16x16x32_bf16(qf1, kb, sx[t], 0, 0, 0);
    }
#pragma unroll
    for (int t = 0; t < 4; ++t) {
#pragma unroll
      for (int r = 0; r < 4; ++r) {
        float p = __expf(sx[t][r] - m_i[r]);
        l_i[r] += p;
        plc[(quad * 4 + r) * 68 + t * 16 + col] = f2bf(p);
      }
    }
    bf16x8 pf0 = *(const bf16x8*)(plc + col * 68 + quad * 8);
    bf16x8 pf1 = *(const bf16x8*)(plc + col * 68 + 32 + quad * 8);
#pragma unroll
    for (int cg = 0; cg < 4; ++cg) {
      const u16* vp = Vbase + (((size_t)(kt >> 6)) * 64 + cg * 16 + col) * 64 + quad * 8;
      bf16x8 v0 = *(const bf16x8*)vp;
      bf16x8 v1 = *(const bf16x8*)(vp + 32);
      acc[cg] = __builtin_amdgcn_mfma_f32_16x16x32_bf16(pf0, v0, acc[cg], 0, 0, 0);
      acc[cg] = __builtin_amdgcn_mfma_f32_16x16x32_bf16(pf1, v1, acc[cg], 0, 0, 0);
    }
  }

#pragma unroll
  for (int r = 0; r < 4; ++r)
#pragma unroll
    for (int off = 1; off < 16; off <<= 1) l_i[r] += __shfl_xor(l_i[r], off, 16);
#pragma unroll
  for (int r = 0; r < 4; ++r) {
    int row = quad * 4 + r;
    Osh[(w * 16 + row) * 64 + col]      = acc[0][r];
    Osh[(w * 16 + row) * 64 + col + 16] = acc[1][r];
    Osh[(w * 16 + row) * 64 + col + 32] = acc[2][r];
    Osh[(w * 16 + row) * 64 + col + 48] = acc[3][r];
    if (col == 0) lsh[w * 16 + row] = l_i[r];
  }
  __syncthreads();

  float g = gamma[0];
  for (int row = w; row < 16; row += WPB) {
    float L = 0.f, val = 0.f;
#pragma unroll
    for (int w2 = 0; w2 < WPB; ++w2) {
      L += lsh[w2 * 16 + row];
      val += Osh[(w2 * 16 + row) * 64 + lane];
    }
    size_t o = xoff + (size_t)(tile + row) * CC + lane;
    out[o] = g * (val / L) + x[o];
  }
}

template <int WPB>
__global__ __launch_bounds__(512) void attn_fb(const float* __restrict__ x,
                                               const float* __restrict__ gamma,
                                               float* __restrict__ out) {
  const int w = threadIdx.x >> 6;
  const int lane = threadIdx.x & 63;
  const int quad = lane >> 4, col = lane & 15;
  const int b = blockIdx.x >> 8;
  const int tile = (blockIdx.x & 255) << 4;

  extern __shared__ char smem[];
  float* Osh = (float*)smem;
  float* msh = Osh + WPB * 1024;
  float* lsh = msh + WPB * 16;
  u16* pl = (u16*)(lsh + WPB * 16) + w * 768;
  u16* vt = (u16*)(lsh + WPB * 16) + WPB * 768 + w * 2176;

  const size_t xoff = (size_t)b * NN * CC;
  const f32x4* x4 = (const f32x4*)(x + xoff);

  bf16x8 qf0, qf1;
  {
    int ri = (tile + col) * 16 + quad * 2;
    qf0 = cvt8(x4[ri], x4[ri + 1]);
    qf1 = cvt8(x4[ri + 8], x4[ri + 9]);
  }
  f32x4 zero = {0.f, 0.f, 0.f, 0.f};
  f32x4 acc0 = zero, acc1 = zero, acc2 = zero, acc3 = zero;
  float m_i[4], l_i[4];
#pragma unroll
  for (int r = 0; r < 4; ++r) { m_i[r] = -1e30f; l_i[r] = 0.f; }

  const int k0 = w * (NN / WPB);
  for (int kt = k0; kt < k0 + NN / WPB; kt += 32) {
    bf16x8 k00, k01, k10, k11;
    {
      int kb = (kt + col) * 16 + quad * 2;
      k00 = cvt8(x4[kb], x4[kb + 1]);
      k01 = cvt8(x4[kb + 8], x4[kb + 9]);
      k10 = cvt8(x4[kb + 256], x4[kb + 257]);
      k11 = cvt8(x4[kb + 264], x4[kb + 265]);
#pragma unroll
      for (int h = 0; h < 2; ++h) {
        bf16x8 va = h ? k10 : k00, vb = h ? k11 : k01;
        int base = (h * 16 + col) * 68 + quad * 8;
        *(bf16x4*)(vt + base) = __builtin_shufflevector(va, va, 0, 1, 2, 3);
        *(bf16x4*)(vt + base + 4) = __builtin_shufflevector(va, va, 4, 5, 6, 7);
        *(bf16x4*)(vt + base + 32) = __builtin_shufflevector(vb, vb, 0, 1, 2, 3);
        *(bf16x4*)(vt + base + 36) = __builtin_shufflevector(vb, vb, 4, 5, 6, 7);
      }
    }
    f32x4 s0 = zero, s1 = zero;
    s0 = __builtin_amdgcn_mfma_f32_16x16x32_bf16(qf0, k00, s0, 0, 0, 0);
    s0 = __builtin_amdgcn_mfma_f32_16x16x32_bf16(qf1, k01, s0, 0, 0, 0);
    s1 = __builtin_amdgcn_mfma_f32_16x16x32_bf16(qf0, k10, s1, 0, 0, 0);
    s1 = __builtin_amdgcn_mfma_f32_16x16x32_bf16(qf1, k11, s1, 0, 0, 0);

    float p0[4], p1[4], alpha[4];
#pragma unroll
    for (int r = 0; r < 4; ++r) {
      float mx = fmaxf(s0[r], s1[r]);
#pragma unroll
      for (int off = 1; off < 16; off <<= 1) mx = fmaxf(mx, __shfl_xor(mx, off, 16));
      float mn = fmaxf(m_i[r], mx);
      alpha[r] = __expf(m_i[r] - mn);
      p0[r] = __expf(s0[r] - mn);
      p1[r] = __expf(s1[r] - mn);
      float rs = p0[r] + p1[r];
#pragma unroll
      for (int off = 1; off < 16; off <<= 1) rs += __shfl_xor(rs, off, 16);
      l_i[r] = l_i[r] * alpha[r] + rs;
      m_i[r] = mn;
    }
#pragma unroll
    for (int r = 0; r < 4; ++r) {
      acc0[r] *= alpha[r]; acc1[r] *= alpha[r];
      acc2[r] *= alpha[r]; acc3[r] *= alpha[r];
    }
#pragma unroll
    for (int r = 0; r < 4; ++r) {
      pl[(quad * 4 + r) * 24 + col] = f2bf(p0[r]);
      pl[384 + (quad * 4 + r) * 24 + col] = f2bf(p1[r]);
    }
    bf16x8 pf = *(const bf16x8*)(pl + (quad >> 1) * 384 + col * 24 + (quad & 1) * 8);

    bf16x8 v0, v1, v2, v3;
#pragma unroll
    for (int j = 0; j < 8; ++j) {
      int rb = (quad * 8 + j) * 68 + col;
      v0[j] = (short)vt[rb];
      v1[j] = (short)vt[rb + 16];
      v2[j] = (short)vt[rb + 32];
      v3[j] = (short)vt[rb + 48];
    }
    acc0 = __builtin_amdgcn_mfma_f32_16x16x32_bf16(pf, v0, acc0, 0, 0, 0);
    acc1 = __builtin_amdgcn_mfma_f32_16x16x32_bf16(pf, v1, acc1, 0, 0, 0);
    acc2 = __builtin_amdgcn_mfma_f32_16x16x32_bf16(pf, v2, acc2, 0, 0, 0);
    acc3 = __builtin_amdgcn_mfma_f32_16x16x32_bf16(pf, v3, acc3, 0, 0, 0);
  }

#pragma unroll
  for (int r = 0; r < 4; ++r) {
    int row = quad * 4 + r;
    Osh[(w * 16 + row) * 64 + col] = acc0[r];
    Osh[(w * 16 + row) * 64 + col + 16] = acc1[r];
    Osh[(w * 16 + row) * 64 + col + 32] = acc2[r];
    Osh[(w * 16 + row) * 64 + col + 48] = acc3[r];
    if (col == 0) { msh[w * 16 + row] = m_i[r]; lsh[w * 16 + row] = l_i[r]; }
  }
  __syncthreads();

  float g = gamma[0];
  for (int row = w; row < 16; row += WPB) {
    float M = -1e30f;
#pragma unroll
    for (int w2 = 0; w2 < WPB; ++w2) M = fmaxf(M, msh[w2 * 16 + row]);
    float L = 0.f, val = 0.f;
#pragma unroll
    for (int w2 = 0; w2 < WPB; ++w2) {
      float e = __expf(msh[w2 * 16 + row] - M);
      L += lsh[w2 * 16 + row] * e;
      val += Osh[(w2 * 16 + row) * 64 + lane] * e;
    }
    size_t o = xoff + (size_t)(tile + row) * CC + lane;
    out[o] = g * (val / L) + x[o];
  }
}

extern "C" void kernel_launch(void* const* d_in, const int* in_sizes, int n_in,
                              void* d_out, int out_size, void* d_ws, size_t ws_size,
                              hipStream_t stream) {
  const float* x = (const float*)d_in[0];
  const float* gamma = (const float*)d_in[1];
  float* out = (float*)d_out;

  constexpr int S = 8;
  constexpr size_t kQV = (size_t)2 * 2 * NN * CC * sizeof(u16);          // 2 MB
  constexpr size_t kOp = (size_t)2 * 32 * S * 128 * 64 * sizeof(u16);    // 8 MB
  constexpr size_t kLp = (size_t)2 * 32 * S * 128 * sizeof(float);       // 256 KB
  if (ws_size >= kQV + kOp + kLp) {
    u16* Qb = (u16*)d_ws;
    u16* Vt = Qb + (size_t)2 * NN * CC;
    u16* Opart = (u16*)((char*)d_ws + kQV);
    float* lpart = (float*)((char*)d_ws + kQV + kOp);
    prep_kernel<<<512, 256, 0, stream>>>(x, Qb, Vt);
    attn_split<S, 3><<<2 * 32 * S, 512, 0, stream>>>(Qb, Vt, Opart, lpart);
    epi_kernel<S><<<(2 * NN * 16) / 256, 256, 0, stream>>>(x, gamma, Opart, lpart, out);
  } else if (ws_size >= kQV) {
    u16* Qb = (u16*)d_ws;
    u16* Vt = Qb + (size_t)2 * NN * CC;
    prep_kernel<<<512, 256, 0, stream>>>(x, Qb, Vt);
    constexpr int SM = 8 * 1024 * 4 + 8 * 16 * 4 + 8 * 2176 * 2;  // 68096 B
    attn_fast<8><<<512, 512, SM, stream>>>(x, gamma, Qb, Vt, out);
  } else {
    constexpr int SM4 = 4 * (1024 + 32) * 4 + 4 * 768 * 2 + 4 * 2176 * 2;
    attn_fb<4><<<512, 256, SM4, stream>>>(x, gamma, out);
  }
}

// Round 9
// 91.598 us; speedup vs baseline: 1.6731x; 1.6731x over previous
//
#include <hip/hip_runtime.h>
#include <hip/hip_bf16.h>
#include <math.h>

// Channel attention: x (2,16,16,16,64) fp32 -> B=2, N=4096, C=64.
// out = gamma * softmax(QQ^T) Q + x.
// v23: kill the dirty-workspace K/V chain. v22's PMC (first visible attn):
// FETCH 34MB/pass from a 2MB dataset, hbm 3.8TB/s, MfmaUtil 10% -> attn is
// HBM-bound on prep->attn DIRTY-LINE handoffs (cross-XCD + the 256MB d_ws
// poison fill evicting L2/L3 every iteration) == pre-registered signature E.
// Fix: DELETE prep/Qb/Vt. attn stages K/V straight from CLEAN fp32 x
// (clean lines serve cross-XCD from L3 without writeback; x = 2MB stays
// resident). One fp32 load pass per 64-key tile feeds BOTH KT (row-major,
// swizzled chunks, v19 reader-compatible) and VT (transposed, pitch-66 =>
// conflict-free b128 PV reads), bf16 via v_cvt_pk_bf16_f32. Reg-staged
// double-buffer, one __syncthreads per tile. Compute body = v21 verbatim
// (32x32x16, S^T QK, register P^T, O^T accum, wk-combine + LDS transpose).
// Fixed harness floor: ~42us d_ws re-poison fill inside the timed window.

#define NN 4096
#define CC 64
#define LOG2E 1.4426950408889634f

typedef __attribute__((ext_vector_type(4))) float f32x4;
typedef __attribute__((ext_vector_type(16))) float f32x16;
typedef __attribute__((ext_vector_type(8))) short bf16x8;
typedef __attribute__((ext_vector_type(4))) short bf16x4;
typedef unsigned short u16;
typedef __attribute__((ext_vector_type(4))) u16 u16x4;
typedef __attribute__((ext_vector_type(8))) u16 u16x8;

__device__ inline u16 f2bf(float f) {  // RNE
  union { float f; unsigned u; } v; v.f = f;
  unsigned r = (v.u + 0x7fffu + ((v.u >> 16) & 1u)) >> 16;
  return (u16)r;
}
__device__ inline float bf2f(short h) {
  union { unsigned u; float f; } v;
  v.u = ((unsigned)(unsigned short)h) << 16;
  return v.f;
}
__device__ inline unsigned cvtpk(float lo, float hi) {  // {bf16(lo)|bf16(hi)<<16}
  unsigned d;
  asm("v_cvt_pk_bf16_f32 %0, %1, %2" : "=v"(d) : "v"(lo), "v"(hi));
  return d;
}
__device__ inline bf16x8 cvt8(f32x4 a, f32x4 b) {
  bf16x8 r;
  r[0] = (short)f2bf(a[0]); r[1] = (short)f2bf(a[1]);
  r[2] = (short)f2bf(a[2]); r[3] = (short)f2bf(a[3]);
  r[4] = (short)f2bf(b[0]); r[5] = (short)f2bf(b[1]);
  r[6] = (short)f2bf(b[2]); r[7] = (short)f2bf(b[3]);
  return r;
}

// ---------------------------------------------------------------------------
// Split flash v23: reads x directly (no prep, no Qb/Vt workspace).
// Block = 8 waves = (wk key-half x wr4 row-quarter), 128 rows; S=8 slices,
// 64-key tiles, ITERS=8, reg-staged LDS double-buffer.
// ---------------------------------------------------------------------------
template <int S>
__global__ __launch_bounds__(512, 4) void attn_split(
    const float* __restrict__ x,
    u16* __restrict__ Opart, float* __restrict__ lpart) {
  constexpr int KPS = NN / S;        // 512
  constexpr int ITERS = KPS / 64;    // 8
  const int lane = threadIdx.x & 63;
  const int w = threadIdx.x >> 6;    // 0..7
  const int wk = w & 1, wr4 = w >> 1;
  const int hf = lane >> 5, l31 = lane & 31, c8 = lane & 7;
  const int blk = blockIdx.x;        // [0, 2*32*S)
  const int b = blk / (32 * S);
  const int rg = (blk / S) & 31;
  const int s = blk % S;

  // KT: [2][64 keys][64 ch] bf16 (16 KB). VT: [2][64 ch][66] bf16 (16.5 KB).
  __shared__ __align__(16) char smem[36864];
  u16* KT = (u16*)smem;              // 2 * 4096
  u16* VT = (u16*)(smem + 16384);    // 2 * 4224

  const float* xb = x + (size_t)b * NN * CC;
  const int row0 = rg * 128 + wr4 * 32;

  // --- Q B-frags from x (pre-scaled by log2e); m = diag of scaled S ---
  // qs[sl][j] = bf16(x[row0+l31][sl*16+hf*8+j] * log2e)
  bf16x8 qs[4];
  float m_sc;
  {
    const float* qp = xb + (size_t)(row0 + l31) * CC;
    float msum = 0.f;
#pragma unroll
    for (int sl = 0; sl < 4; ++sl) {
      bf16x8 t;
#pragma unroll
      for (int j = 0; j < 8; ++j) {
        float a = qp[sl * 16 + hf * 8 + j];
        u16 hs = f2bf(a * LOG2E);
        t[j] = (short)hs;
        // exact diag as MFMA sees it: bf16(K) * bf16(Qs)
        msum += bf2f((short)hs) * bf2f((short)f2bf(a));
      }
      qs[sl] = t;
    }
    msum += __shfl_xor(msum, 32);    // partner holds the other 32 ch
    m_sc = msum;
  }

  f32x16 zero16;
#pragma unroll
  for (int r = 0; r < 16; ++r) zero16[r] = 0.f;
  f32x16 acc[2] = {zero16, zero16};  // O^T partial: cg0 = ch0..31, cg1 = 32..63
  float l_loc = 0.f;

  // --- staging geometry: wave w stages keys [w*8, w*8+8) of each tile ---
  const int lk = w * 8 + (lane >> 3); // local key in 64-tile
  const int chsw = c8 ^ (lk & 7);     // source ch-chunk for KT slot c8
  const float* ksrc = xb + (size_t)(s * KPS + lk) * CC + chsw * 8;

  f32x4 ra, rb;                       // staged fp32 (8 ch of key lk)

#define LOADT(it)                                                            \
  {                                                                          \
    const f32x4* p4 = (const f32x4*)(ksrc + (size_t)(it) * 64 * CC);         \
    ra = p4[0]; rb = p4[1];                                                  \
  }
#define WRITET(p)                                                            \
  {                                                                          \
    bf16x8 kv;                                                               \
    ((unsigned*)&kv)[0] = cvtpk(ra[0], ra[1]);                               \
    ((unsigned*)&kv)[1] = cvtpk(ra[2], ra[3]);                               \
    ((unsigned*)&kv)[2] = cvtpk(rb[0], rb[1]);                               \
    ((unsigned*)&kv)[3] = cvtpk(rb[2], rb[3]);                               \
    *(bf16x8*)&KT[(p) * 4096 + lk * 64 + c8 * 8] = kv;                       \
    u16* vcol = &VT[(p) * 4224 + lk];                                        \
    _Pragma("unroll")                                                        \
    for (int j = 0; j < 8; ++j) vcol[(chsw * 8 + j) * 66] = (u16)kv[j];      \
  }

  LOADT(0)
  WRITET(0)
  if (ITERS > 1) LOADT(1)
  __syncthreads();                    // tile 0 visible

#pragma unroll
  for (int i = 0; i < ITERS; ++i) {
    const int p = i & 1;
    if (i + 1 < ITERS) WRITET(p ^ 1)  // stage tile i+1 into other buffer
    if (i + 2 < ITERS) LOADT(i + 2)   // prefetch fp32 for tile i+2

    // --- QK^T (S^T form): sx[key 16-pat][qrow=l31], keys = wk-half ---
    f32x16 sx = zero16;
    __builtin_amdgcn_s_setprio(1);
#pragma unroll
    for (int sl = 0; sl < 4; ++sl) {
      bf16x8 kf = *(const bf16x8*)&KT[p * 4096 + (wk * 32 + l31) * 64 +
                                      ((sl * 2 + hf) ^ (l31 & 7)) * 8];
      sx = __builtin_amdgcn_mfma_f32_32x32x16_bf16(kf, qs[sl], sx, 0, 0, 0);
    }
    __builtin_amdgcn_s_setprio(0);

    // --- exp2 + l + in-register P^T frags (keys (r&3)+8*(r>>2)+4*hf) ---
    float p16[16];
#pragma unroll
    for (int r = 0; r < 16; ++r) p16[r] = exp2f(sx[r] - m_sc);
#pragma unroll
    for (int r = 0; r < 16; ++r) l_loc += p16[r];
    unsigned own[4][2], sh[4][2];
#pragma unroll
    for (int q = 0; q < 4; ++q) {     // quad q = keys 8q+4hf+0..3
      own[q][0] = cvtpk(p16[4 * q + 0], p16[4 * q + 1]);
      own[q][1] = cvtpk(p16[4 * q + 2], p16[4 * q + 3]);
    }
#pragma unroll
    for (int q = 0; q < 4; ++q) {
      sh[q][0] = (unsigned)__shfl_xor((int)own[q][0], 32);
      sh[q][1] = (unsigned)__shfl_xor((int)own[q][1], 32);
    }
    bf16x8 pf[2];                     // B-frag ks: keys 16ks+8hf+0..7
#pragma unroll
    for (int ks = 0; ks < 2; ++ks) {
      unsigned d0 = hf ? sh[2 * ks + 1][0] : own[2 * ks][0];
      unsigned d1 = hf ? sh[2 * ks + 1][1] : own[2 * ks][1];
      unsigned d2 = hf ? own[2 * ks + 1][0] : sh[2 * ks][0];
      unsigned d3 = hf ? own[2 * ks + 1][1] : sh[2 * ks][1];
      bf16x8 f;
      ((unsigned*)&f)[0] = d0; ((unsigned*)&f)[1] = d1;
      ((unsigned*)&f)[2] = d2; ((unsigned*)&f)[3] = d3;
      pf[ks] = f;
    }

    // --- PV (O^T form): acc[cg] += V^T[ch][key] * P^T[key][qrow] ---
    __builtin_amdgcn_s_setprio(1);
#pragma unroll
    for (int cg = 0; cg < 2; ++cg) {
#pragma unroll
      for (int ks = 0; ks < 2; ++ks) {
        bf16x8 vf = *(const bf16x8*)&VT[p * 4224 + (cg * 32 + l31) * 66 +
                                        (4 * wk + 2 * ks + hf) * 8];
        acc[cg] = __builtin_amdgcn_mfma_f32_32x32x16_bf16(vf, pf[ks], acc[cg], 0, 0, 0);
      }
    }
    __builtin_amdgcn_s_setprio(0);
    __syncthreads();                  // writes of tile i+1 visible; reads of p done
  }
#undef LOADT
#undef WRITET

  // --- combine wk partials + transpose via LDS (reuses staging space) ---
  l_loc += __shfl_xor(l_loc, 32);     // partner half holds other 16 keys
  float* LDSO = (float*)smem;         // [64 ch][132] padded (33792 B)
  float* LDSL = (float*)(smem + 64 * 132 * 4);  // [2][128] (1 KB)
  const int qcol = wr4 * 32 + l31;    // 0..127
  if (wk == 1) {
#pragma unroll
    for (int cg = 0; cg < 2; ++cg)
#pragma unroll
      for (int r = 0; r < 16; ++r) {
        int ch = cg * 32 + (r & 3) + 8 * (r >> 2) + 4 * hf;
        LDSO[ch * 132 + qcol] = acc[cg][r];
      }
  }
  if (lane < 32) LDSL[wk * 128 + qcol] = l_loc;
  __syncthreads();
  if (wk == 0) {
#pragma unroll
    for (int cg = 0; cg < 2; ++cg)
#pragma unroll
      for (int r = 0; r < 16; ++r) {
        int ch = cg * 32 + (r & 3) + 8 * (r >> 2) + 4 * hf;
        LDSO[ch * 132 + qcol] += acc[cg][r];
      }
  }
  __syncthreads();

  size_t pbase = (((size_t)(b * 32 + rg)) * S + s) * (128 * 64);
  size_t lbase = (((size_t)(b * 32 + rg)) * S + s) * 128;
  {
    int row = threadIdx.x >> 2;       // 0..127 (q-row)
    int cq = threadIdx.x & 3;         // 16-ch chunk
    u16x8 o0, o1;
#pragma unroll
    for (int j = 0; j < 8; ++j) {
      o0[j] = f2bf(LDSO[(cq * 16 + j) * 132 + row]);
      o1[j] = f2bf(LDSO[(cq * 16 + 8 + j) * 132 + row]);
    }
    *(u16x8*)(Opart + pbase + (size_t)row * 64 + cq * 16) = o0;
    *(u16x8*)(Opart + pbase + (size_t)row * 64 + cq * 16 + 8) = o1;
  }
  if (threadIdx.x < 128)
    lpart[lbase + threadIdx.x] = LDSL[threadIdx.x] + LDSL[128 + threadIdx.x];
}

// ---------------------------------------------------------------------------
// Epilogue: out = gamma * (sum_s O)/(sum_s l) + x. 512 blocks x 256 threads.
// Opart layout [b][rg=32][S][128][64].
// ---------------------------------------------------------------------------
template <int S>
__global__ __launch_bounds__(256) void epi_kernel(
    const float* __restrict__ x, const float* __restrict__ gamma,
    const u16* __restrict__ Opart, const float* __restrict__ lpart,
    float* __restrict__ out) {
  int t = blockIdx.x * 256 + threadIdx.x;  // [0, B*NN*16)
  int cg = t & 15;
  int n = (t >> 4) & (NN - 1);
  int b = t >> 16;
  int rb = n >> 7, lr = n & 127;
  size_t obase = ((size_t)(b * 32 + rb) * S) * 8192 + (size_t)lr * 64 + cg * 4;
  size_t lbase = ((size_t)(b * 32 + rb) * S) * 128 + lr;
  f32x4 sO = {0.f, 0.f, 0.f, 0.f};
  float sL = 0.f;
#pragma unroll
  for (int s = 0; s < S; ++s) {
    u16x4 o4 = *(const u16x4*)(Opart + obase + (size_t)s * 8192);
    sL += lpart[lbase + (size_t)s * 128];
    sO[0] += bf2f((short)o4[0]); sO[1] += bf2f((short)o4[1]);
    sO[2] += bf2f((short)o4[2]); sO[3] += bf2f((short)o4[3]);
  }
  size_t xi = (((size_t)b * NN + n) * CC + cg * 4);
  f32x4 xv = *(const f32x4*)(x + xi);
  float g = gamma[0], inv = 1.f / sL;
  f32x4 ov;
#pragma unroll
  for (int j = 0; j < 4; ++j) ov[j] = g * (sO[j] * inv) + xv[j];
  *(f32x4*)(((float*)out) + xi) = ov;
}

// ---------------------------------------------------------------------------
// Workspace-free fallback (reads x directly).
// ---------------------------------------------------------------------------
template <int WPB>
__global__ __launch_bounds__(512) void attn_fb(const float* __restrict__ x,
                                               const float* __restrict__ gamma,
                                               float* __restrict__ out) {
  const int w = threadIdx.x >> 6;
  const int lane = threadIdx.x & 63;
  const int quad = lane >> 4, col = lane & 15;
  const int b = blockIdx.x >> 8;
  const int tile = (blockIdx.x & 255) << 4;

  extern __shared__ char smem[];
  float* Osh = (float*)smem;
  float* msh = Osh + WPB * 1024;
  float* lsh = msh + WPB * 16;
  u16* pl = (u16*)(lsh + WPB * 16) + w * 768;
  u16* vt = (u16*)(lsh + WPB * 16) + WPB * 768 + w * 2176;

  const size_t xoff = (size_t)b * NN * CC;
  const f32x4* x4 = (const f32x4*)(x + xoff);

  bf16x8 qf0, qf1;
  {
    int ri = (tile + col) * 16 + quad * 2;
    qf0 = cvt8(x4[ri], x4[ri + 1]);
    qf1 = cvt8(x4[ri + 8], x4[ri + 9]);
  }
  f32x4 zero = {0.f, 0.f, 0.f, 0.f};
  f32x4 acc0 = zero, acc1 = zero, acc2 = zero, acc3 = zero;
  float m_i[4], l_i[4];
#pragma unroll
  for (int r = 0; r < 4; ++r) { m_i[r] = -1e30f; l_i[r] = 0.f; }

  const int k0 = w * (NN / WPB);
  for (int kt = k0; kt < k0 + NN / WPB; kt += 32) {
    bf16x8 k00, k01, k10, k11;
    {
      int kb = (kt + col) * 16 + quad * 2;
      k00 = cvt8(x4[kb], x4[kb + 1]);
      k01 = cvt8(x4[kb + 8], x4[kb + 9]);
      k10 = cvt8(x4[kb + 256], x4[kb + 257]);
      k11 = cvt8(x4[kb + 264], x4[kb + 265]);
#pragma unroll
      for (int h = 0; h < 2; ++h) {
        bf16x8 va = h ? k10 : k00, vb = h ? k11 : k01;
        int base = (h * 16 + col) * 68 + quad * 8;
        *(bf16x4*)(vt + base) = __builtin_shufflevector(va, va, 0, 1, 2, 3);
        *(bf16x4*)(vt + base + 4) = __builtin_shufflevector(va, va, 4, 5, 6, 7);
        *(bf16x4*)(vt + base + 32) = __builtin_shufflevector(vb, vb, 0, 1, 2, 3);
        *(bf16x4*)(vt + base + 36) = __builtin_shufflevector(vb, vb, 4, 5, 6, 7);
      }
    }
    f32x4 s0 = zero, s1 = zero;
    s0 = __builtin_amdgcn_mfma_f32_16x16x32_bf16(qf0, k00, s0, 0, 0, 0);
    s0 = __builtin_amdgcn_mfma_f32_16x16x32_bf16(qf1, k01, s0, 0, 0, 0);
    s1 = __builtin_amdgcn_mfma_f32_16x16x32_bf16(qf0, k10, s1, 0, 0, 0);
    s1 = __builtin_amdgcn_mfma_f32_16x16x32_bf16(qf1, k11, s1, 0, 0, 0);

    float p0[4], p1[4], alpha[4];
#pragma unroll
    for (int r = 0; r < 4; ++r) {
      float mx = fmaxf(s0[r], s1[r]);
#pragma unroll
      for (int off = 1; off < 16; off <<= 1) mx = fmaxf(mx, __shfl_xor(mx, off, 16));
      float mn = fmaxf(m_i[r], mx);
      alpha[r] = __expf(m_i[r] - mn);
      p0[r] = __expf(s0[r] - mn);
      p1[r] = __expf(s1[r] - mn);
      float rs = p0[r] + p1[r];
#pragma unroll
      for (int off = 1; off < 16; off <<= 1) rs += __shfl_xor(rs, off, 16);
      l_i[r] = l_i[r] * alpha[r] + rs;
      m_i[r] = mn;
    }
#pragma unroll
    for (int r = 0; r < 4; ++r) {
      acc0[r] *= alpha[r]; acc1[r] *= alpha[r];
      acc2[r] *= alpha[r]; acc3[r] *= alpha[r];
    }
#pragma unroll
    for (int r = 0; r < 4; ++r) {
      pl[(quad * 4 + r) * 24 + col] = f2bf(p0[r]);
      pl[384 + (quad * 4 + r) * 24 + col] = f2bf(p1[r]);
    }
    bf16x8 pf = *(const bf16x8*)(pl + (quad >> 1) * 384 + col * 24 + (quad & 1) * 8);

    bf16x8 v0, v1, v2, v3;
#pragma unroll
    for (int j = 0; j < 8; ++j) {
      int rb = (quad * 8 + j) * 68 + col;
      v0[j] = (short)vt[rb];
      v1[j] = (short)vt[rb + 16];
      v2[j] = (short)vt[rb + 32];
      v3[j] = (short)vt[rb + 48];
    }
    acc0 = __builtin_amdgcn_mfma_f32_16x16x32_bf16(pf, v0, acc0, 0, 0, 0);
    acc1 = __builtin_amdgcn_mfma_f32_16x16x32_bf16(pf, v1, acc1, 0, 0, 0);
    acc2 = __builtin_amdgcn_mfma_f32_16x16x32_bf16(pf, v2, acc2, 0, 0, 0);
    acc3 = __builtin_amdgcn_mfma_f32_16x16x32_bf16(pf, v3, acc3, 0, 0, 0);
  }

#pragma unroll
  for (int r = 0; r < 4; ++r) {
    int row = quad * 4 + r;
    Osh[(w * 16 + row) * 64 + col] = acc0[r];
    Osh[(w * 16 + row) * 64 + col + 16] = acc1[r];
    Osh[(w * 16 + row) * 64 + col + 32] = acc2[r];
    Osh[(w * 16 + row) * 64 + col + 48] = acc3[r];
    if (col == 0) { msh[w * 16 + row] = m_i[r]; lsh[w * 16 + row] = l_i[r]; }
  }
  __syncthreads();

  float g = gamma[0];
  for (int row = w; row < 16; row += WPB) {
    float M = -1e30f;
#pragma unroll
    for (int w2 = 0; w2 < WPB; ++w2) M = fmaxf(M, msh[w2 * 16 + row]);
    float L = 0.f, val = 0.f;
#pragma unroll
    for (int w2 = 0; w2 < WPB; ++w2) {
      float e = __expf(msh[w2 * 16 + row] - M);
      L += lsh[w2 * 16 + row] * e;
      val += Osh[(w2 * 16 + row) * 64 + lane] * e;
    }
    size_t o = xoff + (size_t)(tile + row) * CC + lane;
    out[o] = g * (val / L) + x[o];
  }
}

extern "C" void kernel_launch(void* const* d_in, const int* in_sizes, int n_in,
                              void* d_out, int out_size, void* d_ws, size_t ws_size,
                              hipStream_t stream) {
  const float* x = (const float*)d_in[0];
  const float* gamma = (const float*)d_in[1];
  float* out = (float*)d_out;

  constexpr int S = 8;
  constexpr size_t kOp = (size_t)2 * 32 * S * 128 * 64 * sizeof(u16);    // 8 MB
  constexpr size_t kLp = (size_t)2 * 32 * S * 128 * sizeof(float);       // 256 KB
  if (ws_size >= kOp + kLp) {
    u16* Opart = (u16*)d_ws;
    float* lpart = (float*)((char*)d_ws + kOp);
    attn_split<S><<<2 * 32 * S, 512, 0, stream>>>(x, Opart, lpart);
    epi_kernel<S><<<(2 * NN * 16) / 256, 256, 0, stream>>>(x, gamma, Opart, lpart, out);
  } else {
    constexpr int SM4 = 4 * (1024 + 32) * 4 + 4 * 768 * 2 + 4 * 2176 * 2;
    attn_fb<4><<<512, 256, SM4, stream>>>(x, gamma, out);
  }
}

// Round 10
// 81.026 us; speedup vs baseline: 1.8914x; 1.1305x over previous
//
#include <hip/hip_runtime.h>
#include <hip/hip_bf16.h>
#include <math.h>

// Channel attention: x (2,16,16,16,64) fp32 -> B=2, N=4096, C=64.
// out = gamma * softmax(QQ^T) Q + x.
// v24 = v16 (best, 81.36us) + ONE change: slice s becomes the SLOW block
// index (s=blk>>7, b=(blk>>6)&1, rg=blk&63).
// Evidence chain: v22 PMC showed attn FETCH=34MB/pass from 2MB unique Qb/Vt
// (~17x HBM re-fetch). If workgroup->XCD were round-robin blk%8, v16's
// s=blk%8 would already colocate slice consumers on one XCD L2 and FETCH
// would be ~4MB -> mapping must be CHUNKED (contiguous blk ranges per XCD;
// HK's chiplet_transform_chunked corroborates). Under chunked, s-slow puts
// XCD k's 128 blocks = exactly slice-k consumers (256KB unique, L2-resident)
// and the linear prep already writes slice k from XCD k (tiles 32k..32k+31)
// -> producer/consumer dirty-local. v23 post-mortem: direct-x reg-staging
// (91.6us) doubled staged bytes + VALU-heavy ds_writes -> rolled back.
// Fixed harness floor: ~42us d_ws re-poison fill inside the timed window.

#define NN 4096
#define CC 64
#define LOG2E 1.4426950408889634f

typedef __attribute__((ext_vector_type(4))) float f32x4;
typedef __attribute__((ext_vector_type(8))) short bf16x8;
typedef __attribute__((ext_vector_type(4))) short bf16x4;
typedef unsigned short u16;
typedef __attribute__((ext_vector_type(4))) u16 u16x4;
typedef __attribute__((ext_vector_type(2))) unsigned u32x2;

__device__ inline u16 f2bf(float f) {  // RNE
  union { float f; unsigned u; } v; v.f = f;
  unsigned r = (v.u + 0x7fffu + ((v.u >> 16) & 1u)) >> 16;
  return (u16)r;
}
__device__ inline float bf2f(short h) {
  union { unsigned u; float f; } v;
  v.u = ((unsigned)(unsigned short)h) << 16;
  return v.f;
}
__device__ inline unsigned fbits(float f) {
  union { float f; unsigned u; } v; v.f = f;
  return v.u;
}
__device__ inline bf16x8 cvt8(f32x4 a, f32x4 b) {
  bf16x8 r;
  r[0] = (short)f2bf(a[0]); r[1] = (short)f2bf(a[1]);
  r[2] = (short)f2bf(a[2]); r[3] = (short)f2bf(a[3]);
  r[4] = (short)f2bf(b[0]); r[5] = (short)f2bf(b[1]);
  r[6] = (short)f2bf(b[2]); r[7] = (short)f2bf(b[3]);
  return r;
}

// ---------------------------------------------------------------------------
// Prep: x -> bf16 Qb[b][n][c] and Vt2[b][n/64][c][n%64]. 512 blocks x 256.
// Linear tile order: under CHUNKED XCD mapping, XCD k writes tiles
// 32k..32k+31 = key-slice k -- already colocated with v24's attn readers.
// ---------------------------------------------------------------------------
__global__ __launch_bounds__(256) void prep_kernel(const float* __restrict__ x,
                                                   u16* __restrict__ Qb,
                                                   u16* __restrict__ Vt) {
  __shared__ u16 t[64][20];
  int b = blockIdx.x >> 8;
  int n0 = (blockIdx.x & 255) << 4;  // 16-row tile
  const f32x4* x4 = (const f32x4*)(x + ((size_t)b * NN + n0) * CC);
  u16* qb = Qb + ((size_t)b * NN + n0) * CC;
  {
    int idx4 = threadIdx.x;          // 256 f32x4 = 16 rows x 16 groups
    int i = idx4 >> 4, cg = idx4 & 15;
    f32x4 v = x4[idx4];
    u16x4 h;
    h[0] = f2bf(v[0]); h[1] = f2bf(v[1]); h[2] = f2bf(v[2]); h[3] = f2bf(v[3]);
    *(u16x4*)(qb + (size_t)i * CC + cg * 4) = h;
    t[cg * 4 + 0][i] = h[0]; t[cg * 4 + 1][i] = h[1];
    t[cg * 4 + 2][i] = h[2]; t[cg * 4 + 3][i] = h[3];
  }
  __syncthreads();
  int kb = n0 >> 6, kw0 = n0 & 63;   // 64-key block / offset within it
  {
    int idx4 = threadIdx.x;          // 256 u16x4 = 64 c x 4 i-groups
    int c = idx4 >> 2, i4 = (idx4 & 3) * 4;
    u16x4 h = *(const u16x4*)(&t[c][i4]);
    *(u16x4*)(Vt + (((size_t)b * (NN / 64) + kb) * 64 + c) * 64 + kw0 + i4) = h;
  }
}

// ---------------------------------------------------------------------------
// Split flash v24: v16 body; block = 4 waves x 16 rows = 64 rows; S slices.
// Slice s is the SLOW index: under chunked XCD mapping, XCD k hosts exactly
// the 128 blocks that read slice k (both batches) -> slice stays in local L2.
// ---------------------------------------------------------------------------
template <int S>
__global__ __launch_bounds__(256, 4) void attn_split(
    const u16* __restrict__ Qb, const u16* __restrict__ Vt,
    u16* __restrict__ Opart, float* __restrict__ lpart) {
  constexpr int KPS = NN / S;        // 512
  constexpr int ITERS = KPS / 64;    // 8
  const int w = threadIdx.x >> 6;    // 0..3
  const int lane = threadIdx.x & 63;
  const int quad = lane >> 4, col = lane & 15;
  const int blk = blockIdx.x;        // [0, 2*64*S)
  const int s = blk >> 7;            // SLOW: key-slice (128 blocks each)
  const int b = (blk >> 6) & 1;
  const int rg = blk & 63;

  __shared__ u16 KT[2][64 * 64];     // 16 KB, XOR-swizzled chunks
  __shared__ u16 VT[2][64 * 64];     // 16 KB
  __shared__ u16 PB[4][16 * 64];     // 8 KB, per-wave, XOR-swizzled

  const u16* Qbase = Qb + (size_t)b * NN * CC;
  const u16* Vbase = Vt + (size_t)b * NN * CC;  // [NN/64][64][64]
  const int row0 = rg * 64 + w * 16;

  // --- Q B-frag (pre-scaled by log2e); m = diag of scaled S (scalar/lane) ---
  bf16x8 qs0, qs1;
  float m_sc;
  {
    const u16* qp = Qbase + (size_t)(row0 + col) * CC + quad * 8;
    bf16x8 r0 = *(const bf16x8*)qp;
    bf16x8 r1 = *(const bf16x8*)(qp + 32);
    float msum = 0.f;
#pragma unroll
    for (int j = 0; j < 8; ++j) {
      float a0 = bf2f(r0[j]), a1 = bf2f(r1[j]);
      u16 h0 = f2bf(a0 * LOG2E), h1 = f2bf(a1 * LOG2E);
      qs0[j] = (short)h0; qs1[j] = (short)h1;
      msum += bf2f((short)h0) * a0 + bf2f((short)h1) * a1;
    }
    msum += __shfl_xor(msum, 16);
    msum += __shfl_xor(msum, 32);  // every lane: full diag for qrow=col
    m_sc = msum;
  }

  f32x4 zero = {0.f, 0.f, 0.f, 0.f};
  f32x4 acc[4] = {zero, zero, zero, zero};
  f32x4 accl = zero;                           // l row-sums via ones-B MFMA
  f32x4 cinit = {-m_sc, -m_sc, -m_sc, -m_sc};  // S - m out of the matrix pipe
  bf16x8 onesb;
#pragma unroll
  for (int j = 0; j < 8; ++j) onesb[j] = (short)0x3F80;  // bf16 1.0

  // --- staging: wave w covers keys/chs [w*16, w*16+16) of the 64-tile ---
  const int kk = lane >> 3;          // 0..7 local row in 8-row group
  const int sw = (lane & 7) ^ kk;    // XOR-swizzled 16B chunk
  const u16* kptr = Qbase + (size_t)(s * KPS + w * 16 + kk) * CC + sw * 8;
  const u16* vptr = Vbase + ((size_t)(s * KPS >> 6) * 64 + (w * 16 + kk)) * 64 + sw * 8;

#define STAGE(p, kp, vp)                                                      \
  {                                                                           \
    _Pragma("unroll")                                                         \
    for (int g = 0; g < 2; ++g) {                                             \
      __builtin_amdgcn_global_load_lds(                                       \
          (const __attribute__((address_space(1))) unsigned*)((kp) + g * 512),\
          (__attribute__((address_space(3))) unsigned*)&KT[p][(w * 16 + g * 8) * 64], \
          16, 0, 0);                                                          \
      __builtin_amdgcn_global_load_lds(                                       \
          (const __attribute__((address_space(1))) unsigned*)((vp) + g * 512),\
          (__attribute__((address_space(3))) unsigned*)&VT[p][(w * 16 + g * 8) * 64], \
          16, 0, 0);                                                          \
    }                                                                         \
  }

  STAGE(0, kptr, vptr)                       // tile 0: 4 gll outstanding
  STAGE(1, kptr + 4096, vptr + 4096)         // tile 1: 8 outstanding
  const int cs = col & 7;
  u16* PBw = &PB[w][0];

#pragma unroll
  for (int i = 0; i < ITERS; ++i) {
    // tile i's 4 gll done; tile i+1's 4 stay in flight (never drain mid-loop)
    if (i + 1 < ITERS)
      asm volatile("s_waitcnt vmcnt(4)" ::: "memory");
    else
      asm volatile("s_waitcnt vmcnt(0)" ::: "memory");
    __builtin_amdgcn_sched_barrier(0);
    __builtin_amdgcn_s_barrier();            // all waves: tile i in LDS
    __builtin_amdgcn_sched_barrier(0);
    const int p = i & 1;

    // --- QK^T (S^T form: A=K, B=Q), C-init = -m_sc ---
    f32x4 sx[4];
    __builtin_amdgcn_s_setprio(1);
#pragma unroll
    for (int t = 0; t < 4; ++t) {
      bf16x8 ka = *(const bf16x8*)&KT[p][(t * 16 + col) * 64 + (quad ^ cs) * 8];
      bf16x8 kb = *(const bf16x8*)&KT[p][(t * 16 + col) * 64 + ((quad + 4) ^ cs) * 8];
      sx[t] = __builtin_amdgcn_mfma_f32_16x16x32_bf16(ka, qs0, cinit, 0, 0, 0);
      sx[t] = __builtin_amdgcn_mfma_f32_16x16x32_bf16(kb, qs1, sx[t], 0, 0, 0);
    }
    __builtin_amdgcn_s_setprio(0);
    // --- exp2 + swizzled packed P-write ---
#pragma unroll
    for (int t = 0; t < 4; ++t) {
      f32x4 pv;
#pragma unroll
      for (int r = 0; r < 4; ++r) pv[r] = exp2f(sx[t][r]);
      u32x2 d;
      d[0] = __builtin_amdgcn_perm(fbits(pv[1]), fbits(pv[0]), 0x07060302u);
      d[1] = __builtin_amdgcn_perm(fbits(pv[3]), fbits(pv[2]), 0x07060302u);
      // keys t*16+quad*4..+3 = chunk (t*2 + (quad>>1)), half (quad&1)
      *(u32x2*)&PBw[col * 64 + ((t * 2 + (quad >> 1)) ^ cs) * 8 + (quad & 1) * 4] = d;
    }
    // --- P A-frags (per-wave DS in-order; swizzled chunk addressing) ---
    bf16x8 pf0 = *(const bf16x8*)&PBw[col * 64 + (quad ^ cs) * 8];
    bf16x8 pf1 = *(const bf16x8*)&PBw[col * 64 + ((quad + 4) ^ cs) * 8];
    __builtin_amdgcn_s_setprio(1);
    // l += rowsum(P) on the matrix pipe
    accl = __builtin_amdgcn_mfma_f32_16x16x32_bf16(pf0, onesb, accl, 0, 0, 0);
    accl = __builtin_amdgcn_mfma_f32_16x16x32_bf16(pf1, onesb, accl, 0, 0, 0);
    // --- PV: O[16][64] += P[16][64] * V[64][64] ---
#pragma unroll
    for (int cg = 0; cg < 4; ++cg) {
      bf16x8 va = *(const bf16x8*)&VT[p][(cg * 16 + col) * 64 + (quad ^ cs) * 8];
      bf16x8 vb = *(const bf16x8*)&VT[p][(cg * 16 + col) * 64 + ((quad + 4) ^ cs) * 8];
      acc[cg] = __builtin_amdgcn_mfma_f32_16x16x32_bf16(pf0, va, acc[cg], 0, 0, 0);
      acc[cg] = __builtin_amdgcn_mfma_f32_16x16x32_bf16(pf1, vb, acc[cg], 0, 0, 0);
    }
    __builtin_amdgcn_s_setprio(0);
    // all waves done READING buffer p before tile i+2 overwrites it.
    __builtin_amdgcn_sched_barrier(0);
    __builtin_amdgcn_s_barrier();
    __builtin_amdgcn_sched_barrier(0);
    if (i + 2 < ITERS) STAGE(p, kptr + 8192, vptr + 8192)
    kptr += 4096; vptr += 4096;
  }
#undef STAGE

  // --- write partials; accl[r] = l for row quad*4+r (any col) ---
  size_t pbase = (((size_t)(b * 64 + rg)) * S + s) * (64 * 64);
  size_t lbase = (((size_t)(b * 64 + rg)) * S + s) * 64;
  if (col == 0) {
#pragma unroll
    for (int r = 0; r < 4; ++r) lpart[lbase + w * 16 + quad * 4 + r] = accl[r];
  }
#pragma unroll
  for (int r = 0; r < 4; ++r) {
    int lr = w * 16 + quad * 4 + r;
    size_t o = pbase + (size_t)lr * 64;
    Opart[o + col]      = f2bf(acc[0][r]);
    Opart[o + col + 16] = f2bf(acc[1][r]);
    Opart[o + col + 32] = f2bf(acc[2][r]);
    Opart[o + col + 48] = f2bf(acc[3][r]);
  }
}

// ---------------------------------------------------------------------------
// Epilogue: out = gamma * (sum_s O)/(sum_s l) + x. 512 blocks x 256 threads.
// ---------------------------------------------------------------------------
template <int S>
__global__ __launch_bounds__(256) void epi_kernel(
    const float* __restrict__ x, const float* __restrict__ gamma,
    const u16* __restrict__ Opart, const float* __restrict__ lpart,
    float* __restrict__ out) {
  int t = blockIdx.x * 256 + threadIdx.x;  // [0, B*NN*16)
  int cg = t & 15;
  int n = (t >> 4) & (NN - 1);
  int b = t >> 16;
  int rb = n >> 6, lr = n & 63;
  size_t obase = ((size_t)(b * 64 + rb) * S) * 4096 + (size_t)lr * 64 + cg * 4;
  size_t lbase = ((size_t)(b * 64 + rb) * S) * 64 + lr;
  f32x4 sO = {0.f, 0.f, 0.f, 0.f};
  float sL = 0.f;
#pragma unroll
  for (int s = 0; s < S; ++s) {
    u16x4 o4 = *(const u16x4*)(Opart + obase + (size_t)s * 4096);
    sL += lpart[lbase + s * 64];
    sO[0] += bf2f((short)o4[0]); sO[1] += bf2f((short)o4[1]);
    sO[2] += bf2f((short)o4[2]); sO[3] += bf2f((short)o4[3]);
  }
  size_t xi = (((size_t)b * NN + n) * CC + cg * 4);
  f32x4 xv = *(const f32x4*)(x + xi);
  float g = gamma[0], inv = 1.f / sL;
  f32x4 ov;
#pragma unroll
  for (int j = 0; j < 4; ++j) ov[j] = g * (sO[j] * inv) + xv[j];
  *(f32x4*)(((float*)out) + xi) = ov;
}

// ---------------------------------------------------------------------------
// Tier B (2MB <= ws): single-kernel path. Tier C: workspace-free.
// ---------------------------------------------------------------------------
template <int WPB>
__global__ __launch_bounds__(WPB * 64, 4) void attn_fast(
    const float* __restrict__ x, const float* __restrict__ gamma,
    const u16* __restrict__ Qb, const u16* __restrict__ Vt,
    float* __restrict__ out) {
  const int w = threadIdx.x >> 6;
  const int lane = threadIdx.x & 63;
  const int quad = lane >> 4, col = lane & 15;
  const int b = blockIdx.x >> 8;
  const int tile = (blockIdx.x & 255) << 4;

  extern __shared__ char smem[];
  float* Osh = (float*)smem;
  float* lsh = Osh + WPB * 1024;
  u16* pl = (u16*)(lsh + WPB * 16) + w * 2176;

  const size_t xoff = (size_t)b * NN * CC;
  const u16* Qbase = Qb + xoff;
  const u16* Vbase = Vt + xoff;

  bf16x8 qf0 = *(const bf16x8*)(Qbase + (size_t)(tile + col) * CC + quad * 8);
  bf16x8 qf1 = *(const bf16x8*)(Qbase + (size_t)(tile + col) * CC + 32 + quad * 8);

  float msum = 0.f;
#pragma unroll
  for (int j = 0; j < 8; ++j) {
    float a = bf2f(qf0[j]), c = bf2f(qf1[j]);
    msum += a * a + c * c;
  }
  msum += __shfl_xor(msum, 16);
  msum += __shfl_xor(msum, 32);
  float m_i[4];
#pragma unroll
  for (int r = 0; r < 4; ++r) m_i[r] = __shfl(msum, quad * 4 + r);

  f32x4 zero = {0.f, 0.f, 0.f, 0.f};
  f32x4 acc[4] = {zero, zero, zero, zero};
  float l_i[4] = {0.f, 0.f, 0.f, 0.f};

  const int k0 = w * (NN / WPB);
#pragma unroll 2
  for (int kt = k0; kt < k0 + NN / WPB; kt += 64) {
    u16* plc = pl + ((kt >> 6) & 1) * 1088;
    f32x4 sx[4];
#pragma unroll
    for (int t = 0; t < 4; ++t) {
      const u16* kp = Qbase + (size_t)(kt + t * 16 + col) * CC + quad * 8;
      bf16x8 ka = *(const bf16x8*)kp;
      bf16x8 kb = *(const bf16x8*)(kp + 32);
      sx[t] = __builtin_amdgcn_mfma_f32_16x16x32_bf16(qf0, ka, zero, 0, 0, 0);
      sx[t] = __builtin_amdgcn_mfma_f32_16x16x32_bf16(qf1, kb, sx[t], 0, 0, 0);
    }
#pragma unroll
    for (int t = 0; t < 4; ++t) {
#pragma unroll
      for (int r = 0; r < 4; ++r) {
        float p = __expf(sx[t][r] - m_i[r]);
        l_i[r] += p;
        plc[(quad * 4 + r) * 68 + t * 16 + col] = f2bf(p);
      }
    }
    bf16x8 pf0 = *(const bf16x8*)(plc + col * 68 + quad * 8);
    bf16x8 pf1 = *(const bf16x8*)(plc + col * 68 + 32 + quad * 8);
#pragma unroll
    for (int cg = 0; cg < 4; ++cg) {
      const u16* vp = Vbase + (((size_t)(kt >> 6)) * 64 + cg * 16 + col) * 64 + quad * 8;
      bf16x8 v0 = *(const bf16x8*)vp;
      bf16x8 v1 = *(const bf16x8*)(vp + 32);
      acc[cg] = __builtin_amdgcn_mfma_f32_16x16x32_bf16(pf0, v0, acc[cg], 0, 0, 0);
      acc[cg] = __builtin_amdgcn_mfma_f32_16x16x32_bf16(pf1, v1, acc[cg], 0, 0, 0);
    }
  }

#pragma unroll
  for (int r = 0; r < 4; ++r)
#pragma unroll
    for (int off = 1; off < 16; off <<= 1) l_i[r] += __shfl_xor(l_i[r], off, 16);
#pragma unroll
  for (int r = 0; r < 4; ++r) {
    int row = quad * 4 + r;
    Osh[(w * 16 + row) * 64 + col]      = acc[0][r];
    Osh[(w * 16 + row) * 64 + col + 16] = acc[1][r];
    Osh[(w * 16 + row) * 64 + col + 32] = acc[2][r];
    Osh[(w * 16 + row) * 64 + col + 48] = acc[3][r];
    if (col == 0) lsh[w * 16 + row] = l_i[r];
  }
  __syncthreads();

  float g = gamma[0];
  for (int row = w; row < 16; row += WPB) {
    float L = 0.f, val = 0.f;
#pragma unroll
    for (int w2 = 0; w2 < WPB; ++w2) {
      L += lsh[w2 * 16 + row];
      val += Osh[(w2 * 16 + row) * 64 + lane];
    }
    size_t o = xoff + (size_t)(tile + row) * CC + lane;
    out[o] = g * (val / L) + x[o];
  }
}

template <int WPB>
__global__ __launch_bounds__(512) void attn_fb(const float* __restrict__ x,
                                               const float* __restrict__ gamma,
                                               float* __restrict__ out) {
  const int w = threadIdx.x >> 6;
  const int lane = threadIdx.x & 63;
  const int quad = lane >> 4, col = lane & 15;
  const int b = blockIdx.x >> 8;
  const int tile = (blockIdx.x & 255) << 4;

  extern __shared__ char smem[];
  float* Osh = (float*)smem;
  float* msh = Osh + WPB * 1024;
  float* lsh = msh + WPB * 16;
  u16* pl = (u16*)(lsh + WPB * 16) + w * 768;
  u16* vt = (u16*)(lsh + WPB * 16) + WPB * 768 + w * 2176;

  const size_t xoff = (size_t)b * NN * CC;
  const f32x4* x4 = (const f32x4*)(x + xoff);

  bf16x8 qf0, qf1;
  {
    int ri = (tile + col) * 16 + quad * 2;
    qf0 = cvt8(x4[ri], x4[ri + 1]);
    qf1 = cvt8(x4[ri + 8], x4[ri + 9]);
  }
  f32x4 zero = {0.f, 0.f, 0.f, 0.f};
  f32x4 acc0 = zero, acc1 = zero, acc2 = zero, acc3 = zero;
  float m_i[4], l_i[4];
#pragma unroll
  for (int r = 0; r < 4; ++r) { m_i[r] = -1e30f; l_i[r] = 0.f; }

  const int k0 = w * (NN / WPB);
  for (int kt = k0; kt < k0 + NN / WPB; kt += 32) {
    bf16x8 k00, k01, k10, k11;
    {
      int kb = (kt + col) * 16 + quad * 2;
      k00 = cvt8(x4[kb], x4[kb + 1]);
      k01 = cvt8(x4[kb + 8], x4[kb + 9]);
      k10 = cvt8(x4[kb + 256], x4[kb + 257]);
      k11 = cvt8(x4[kb + 264], x4[kb + 265]);
#pragma unroll
      for (int h = 0; h < 2; ++h) {
        bf16x8 va = h ? k10 : k00, vb = h ? k11 : k01;
        int base = (h * 16 + col) * 68 + quad * 8;
        *(bf16x4*)(vt + base) = __builtin_shufflevector(va, va, 0, 1, 2, 3);
        *(bf16x4*)(vt + base + 4) = __builtin_shufflevector(va, va, 4, 5, 6, 7);
        *(bf16x4*)(vt + base + 32) = __builtin_shufflevector(vb, vb, 0, 1, 2, 3);
        *(bf16x4*)(vt + base + 36) = __builtin_shufflevector(vb, vb, 4, 5, 6, 7);
      }
    }
    f32x4 s0 = zero, s1 = zero;
    s0 = __builtin_amdgcn_mfma_f32_16x16x32_bf16(qf0, k00, s0, 0, 0, 0);
    s0 = __builtin_amdgcn_mfma_f32_16x16x32_bf16(qf1, k01, s0, 0, 0, 0);
    s1 = __builtin_amdgcn_mfma_f32_16x16x32_bf16(qf0, k10, s1, 0, 0, 0);
    s1 = __builtin_amdgcn_mfma_f32_16x16x32_bf16(qf1, k11, s1, 0, 0, 0);

    float p0[4], p1[4], alpha[4];
#pragma unroll
    for (int r = 0; r < 4; ++r) {
      float mx = fmaxf(s0[r], s1[r]);
#pragma unroll
      for (int off = 1; off < 16; off <<= 1) mx = fmaxf(mx, __shfl_xor(mx, off, 16));
      float mn = fmaxf(m_i[r], mx);
      alpha[r] = __expf(m_i[r] - mn);
      p0[r] = __expf(s0[r] - mn);
      p1[r] = __expf(s1[r] - mn);
      float rs = p0[r] + p1[r];
#pragma unroll
      for (int off = 1; off < 16; off <<= 1) rs += __shfl_xor(rs, off, 16);
      l_i[r] = l_i[r] * alpha[r] + rs;
      m_i[r] = mn;
    }
#pragma unroll
    for (int r = 0; r < 4; ++r) {
      acc0[r] *= alpha[r]; acc1[r] *= alpha[r];
      acc2[r] *= alpha[r]; acc3[r] *= alpha[r];
    }
#pragma unroll
    for (int r = 0; r < 4; ++r) {
      pl[(quad * 4 + r) * 24 + col] = f2bf(p0[r]);
      pl[384 + (quad * 4 + r) * 24 + col] = f2bf(p1[r]);
    }
    bf16x8 pf = *(const bf16x8*)(pl + (quad >> 1) * 384 + col * 24 + (quad & 1) * 8);

    bf16x8 v0, v1, v2, v3;
#pragma unroll
    for (int j = 0; j < 8; ++j) {
      int rb = (quad * 8 + j) * 68 + col;
      v0[j] = (short)vt[rb];
      v1[j] = (short)vt[rb + 16];
      v2[j] = (short)vt[rb + 32];
      v3[j] = (short)vt[rb + 48];
    }
    acc0 = __builtin_amdgcn_mfma_f32_16x16x32_bf16(pf, v0, acc0, 0, 0, 0);
    acc1 = __builtin_amdgcn_mfma_f32_16x16x32_bf16(pf, v1, acc1, 0, 0, 0);
    acc2 = __builtin_amdgcn_mfma_f32_16x16x32_bf16(pf, v2, acc2, 0, 0, 0);
    acc3 = __builtin_amdgcn_mfma_f32_16x16x32_bf16(pf, v3, acc3, 0, 0, 0);
  }

#pragma unroll
  for (int r = 0; r < 4; ++r) {
    int row = quad * 4 + r;
    Osh[(w * 16 + row) * 64 + col] = acc0[r];
    Osh[(w * 16 + row) * 64 + col + 16] = acc1[r];
    Osh[(w * 16 + row) * 64 + col + 32] = acc2[r];
    Osh[(w * 16 + row) * 64 + col + 48] = acc3[r];
    if (col == 0) { msh[w * 16 + row] = m_i[r]; lsh[w * 16 + row] = l_i[r]; }
  }
  __syncthreads();

  float g = gamma[0];
  for (int row = w; row < 16; row += WPB) {
    float M = -1e30f;
#pragma unroll
    for (int w2 = 0; w2 < WPB; ++w2) M = fmaxf(M, msh[w2 * 16 + row]);
    float L = 0.f, val = 0.f;
#pragma unroll
    for (int w2 = 0; w2 < WPB; ++w2) {
      float e = __expf(msh[w2 * 16 + row] - M);
      L += lsh[w2 * 16 + row] * e;
      val += Osh[(w2 * 16 + row) * 64 + lane] * e;
    }
    size_t o = xoff + (size_t)(tile + row) * CC + lane;
    out[o] = g * (val / L) + x[o];
  }
}

extern "C" void kernel_launch(void* const* d_in, const int* in_sizes, int n_in,
                              void* d_out, int out_size, void* d_ws, size_t ws_size,
                              hipStream_t stream) {
  const float* x = (const float*)d_in[0];
  const float* gamma = (const float*)d_in[1];
  float* out = (float*)d_out;

  constexpr int S = 8;
  constexpr size_t kQV = (size_t)2 * 2 * NN * CC * sizeof(u16);         // 2 MB
  constexpr size_t kOp = (size_t)2 * 64 * S * 64 * 64 * sizeof(u16);    // 8 MB
  constexpr size_t kLp = (size_t)2 * 64 * S * 64 * sizeof(float);       // 256 KB
  if (ws_size >= kQV + kOp + kLp) {
    u16* Qb = (u16*)d_ws;
    u16* Vt = Qb + (size_t)2 * NN * CC;
    u16* Opart = (u16*)((char*)d_ws + kQV);
    float* lpart = (float*)((char*)d_ws + kQV + kOp);
    prep_kernel<<<512, 256, 0, stream>>>(x, Qb, Vt);
    attn_split<S><<<2 * 64 * S, 256, 0, stream>>>(Qb, Vt, Opart, lpart);
    epi_kernel<S><<<(2 * NN * 16) / 256, 256, 0, stream>>>(x, gamma, Opart, lpart, out);
  } else if (ws_size >= kQV) {
    u16* Qb = (u16*)d_ws;
    u16* Vt = Qb + (size_t)2 * NN * CC;
    prep_kernel<<<512, 256, 0, stream>>>(x, Qb, Vt);
    constexpr int SM = 8 * 1024 * 4 + 8 * 16 * 4 + 8 * 2176 * 2;  // 68096 B
    attn_fast<8><<<512, 512, SM, stream>>>(x, gamma, Qb, Vt, out);
  } else {
    constexpr int SM4 = 4 * (1024 + 32) * 4 + 4 * 768 * 2 + 4 * 2176 * 2;
    attn_fb<4><<<512, 256, SM4, stream>>>(x, gamma, out);
  }
}